// Round 8
// baseline (53.758 us; speedup 1.0000x reference)
//
#include <hip/hip_runtime.h>
#include <math.h>

#define NOUT 64
#define NIN  64
#define HH   32
#define WW   32
#define XSTR 137                        // LDS row stride (odd -> conflict-free scatter)
#define REPL 3                          // measurement probe: 3 identical replicas
#define OUTSZ (NOUT * HH * WW)          // 65536 floats per replica output

// ---- R6 structure, replicated x3 so kan_main outlasts the harness poison-fills
// ---- and its rocprof counters appear in the top-5. Replica 0 -> d_out,
// ---- replicas 1,2 -> d_ws (disjoint, dead). Per-replica mapping identical to R6.
__global__ __launch_bounds__(512, 8) void kan_main(const float* __restrict__ x,
                                                   const float* __restrict__ wn,
                                                   const float* __restrict__ wd,
                                                   float* __restrict__ out,
                                                   float* __restrict__ ws) {
    __shared__ float xt[NIN * XSTR];    // 35072 B: xt[c][pos], pos = t*34+col
    __shared__ float red[512];

    int bid   = blockIdx.x;
    int rep   = bid >> 10;              // replica 0..2
    int inner = bid & 1023;             // identical to R6's block id
    // bijective XCD-chunked swizzle (1024 per replica; rep offset 1024 % 8 == 0
    // keeps physical XCD assignment identical across replicas)
    int wgid = (inner & 7) * 128 + (inner >> 3);
    int f    = wgid >> 4;
    int band = wgid & 15;
    int i0   = band * 2;

    float* dst = (rep == 0) ? out : (ws + (size_t)(rep - 1) * OUTSZ);

    int tid = threadIdx.x;

    // ---- stage x tile: 8704 floats = 17 * 512; global reads lane=c coalesced ----
#pragma unroll
    for (int k = 0; k < 17; ++k) {
        int idx = k * 512 + tid;
        int c   = idx & 63;
        int pos = idx >> 6;             // 0..135
        int t   = pos / 34;
        int col = pos % 34;
        int gi  = i0 - 1 + t;
        int gj  = col - 1;
        float v = 0.0f;
        if (gi >= 0 && gi < HH && gj >= 0 && gj < WW)
            v = x[(gi * WW + gj) * NIN + c];
        xt[c * XSTR + pos] = v;
    }
    __syncthreads();

    int lane = tid & 63;
    int wv   = __builtin_amdgcn_readfirstlane(tid >> 6);  // c-group 0..7 (SGPR)
    int r    = lane >> 5;
    int j    = lane & 31;

    float acc = 0.0f;

    const float* wnf = wn + (size_t)(f * NIN + wv * 8) * 54;
    const float* wdf = wd + (size_t)(f * NIN + wv * 8) * 36;

    for (int cc = 0; cc < 8; ++cc) {
        const float* wnc = wnf + cc * 54;   // uniform -> s_load
        const float* wdc = wdf + cc * 36;
        const float* xc  = &xt[(wv * 8 + cc) * XSTR + r * 34 + j];
#pragma unroll
        for (int a = 0; a < 3; ++a) {
#pragma unroll
            for (int b = 0; b < 3; ++b) {
                const int ab = a * 3 + b;
                float xv = xc[a * 34 + b];          // ds_read_b32, imm offset
                float pn = fmaf(wnc[ab * 6 + 5], xv, wnc[ab * 6 + 4]);
                pn = fmaf(pn, xv, wnc[ab * 6 + 3]);
                pn = fmaf(pn, xv, wnc[ab * 6 + 2]);
                pn = fmaf(pn, xv, wnc[ab * 6 + 1]);
                pn = fmaf(pn, xv, wnc[ab * 6 + 0]);
                float qn = fmaf(wdc[ab * 4 + 3], xv, wdc[ab * 4 + 2]);
                qn = fmaf(qn, xv, wdc[ab * 4 + 1]);
                qn = fmaf(qn, xv, wdc[ab * 4 + 0]);
                float den = 1.0f + fabsf(xv * qn);
                acc = fmaf(pn, __builtin_amdgcn_rcpf(den), acc);
            }
        }
    }

    // ---- reduce the 8 c-group partials per pixel; write once, coalesced ----
    red[tid] = acc;
    __syncthreads();
    if (tid < 64) {
        float s = red[tid]       + red[tid + 64]  + red[tid + 128] + red[tid + 192]
                + red[tid + 256] + red[tid + 320] + red[tid + 384] + red[tid + 448];
        int rr = tid >> 5;
        int jj = tid & 31;
        dst[f * (HH * WW) + (i0 + rr) * WW + jj] = s;
    }
}

extern "C" void kernel_launch(void* const* d_in, const int* in_sizes, int n_in,
                              void* d_out, int out_size, void* d_ws, size_t ws_size,
                              hipStream_t stream) {
    const float* x  = (const float*)d_in[0];
    const float* wn = (const float*)d_in[1];
    const float* wd = (const float*)d_in[2];
    float* out = (float*)d_out;
    float* ws  = (float*)d_ws;
    (void)in_sizes; (void)n_in; (void)out_size; (void)ws_size;

    kan_main<<<1024 * REPL, 512, 0, stream>>>(x, wn, wd, out, ws);
}

// Round 10
// 24.108 us; speedup vs baseline: 2.2299x; 2.2299x over previous
//
#include <hip/hip_runtime.h>
#include <math.h>

#define NOUT 64
#define NIN  64
#define HH   32
#define WW   32
#define XCPL 205                         // x plane stride per channel (words, odd)
#define XROWS 6
#define XCOLS 34
#define XWORDS (XROWS * XCOLS * NIN)     // 13056
#define WREC 12                          // words per (c,ab) record: a0..a5 b0..b3 pad pad
#define NBLK 512                         // 64 f * 8 four-row bands

typedef float f4 __attribute__((ext_vector_type(4)));

// block = 1024 thr = (f, 4-row band); 16 waves = 8 c-groups x 2 row-halves;
// lane = pixel (2 rows x 32 cols per wave). x AND weights both in LDS ->
// hot loop is pure ds_read (in-order lgkmcnt, fine-grained waits) + VALU.
__global__ __launch_bounds__(1024, 8) void kan_main(const float* __restrict__ x,
                                                    const float* __restrict__ wn,
                                                    const float* __restrict__ wd,
                                                    float* __restrict__ out) {
    __shared__ float xt[NIN * XCPL];                    // 52480 B
    __shared__ __align__(16) float wl[NIN * 9 * WREC];  // 27648 B; reused for reduction

    // bijective XCD-chunked swizzle: 512 blocks, 64 per XCD -> 8 f's per XCD L2
    int bid  = blockIdx.x;
    int wgid = (bid & 7) * (NBLK / 8) + (bid >> 3);
    int f    = wgid >> 3;
    int band = wgid & 7;
    int i0   = band * 4;

    int tid = threadIdx.x;

    // ---- stage x: rows i0-1..i0+4, cols -1..32, all 64 c; reads c-coalesced;
    // ---- LDS writes at odd stride 205 -> 2-way max (free) ----
    for (int k = 0; k < 13; ++k) {
        int idx = k * 1024 + tid;
        if (idx < XWORDS) {
            int c   = idx & 63;
            int t   = idx >> 6;                  // 0..203
            int row = t / 34;
            int col = t % 34;
            int gi  = i0 - 1 + row;
            int gj  = col - 1;
            float v = 0.0f;
            if (gi >= 0 && gi < HH && gj >= 0 && gj < WW)
                v = x[(gi * WW + gj) * NIN + c];
            xt[c * XCPL + row * 34 + col] = v;
        }
    }
    // ---- stage weights for this f, packed [c][ab][12] (16B-aligned records) ----
    const float* wnf = wn + (size_t)f * (NIN * 54);
    for (int k = 0; k < 4; ++k) {
        int t = k * 1024 + tid;
        if (t < NIN * 54) {
            int c   = t / 54;
            int rem = t - c * 54;
            int ab  = rem / 6;
            int n   = rem - ab * 6;
            wl[(c * 9 + ab) * WREC + n] = wnf[t];
        }
    }
    const float* wdf = wd + (size_t)f * (NIN * 36);
    for (int k = 0; k < 3; ++k) {
        int t = k * 1024 + tid;
        if (t < NIN * 36) {
            int c   = t / 36;
            int rem = t - c * 36;
            int ab  = rem / 4;
            int n   = rem - ab * 4;
            wl[(c * 9 + ab) * WREC + 6 + n] = wdf[t];
        }
    }
    __syncthreads();

    int lane = tid & 63;
    int wv   = __builtin_amdgcn_readfirstlane(tid >> 6);  // 0..15
    int cgrp = wv & 7;
    int half = wv >> 3;
    int r    = half * 2 + (lane >> 5);   // pixel row within band: 0..3
    int j    = lane & 31;                // pixel col

    float acc = 0.0f;

#pragma unroll
    for (int cc = 0; cc < 8; ++cc) {
        int c = cgrp * 8 + cc;
        const float* xb = &xt[c * XCPL + r * 34 + j];
        float xw[9];
        xw[0] = xb[0];  xw[1] = xb[1];  xw[2] = xb[2];
        xw[3] = xb[34]; xw[4] = xb[35]; xw[5] = xb[36];
        xw[6] = xb[68]; xw[7] = xb[69]; xw[8] = xb[70];

        const f4* wr = (const f4*)&wl[c * 9 * WREC];      // uniform addr -> broadcast
#pragma unroll
        for (int ab = 0; ab < 9; ++ab) {
            f4 w0 = wr[ab * 3 + 0];      // a0 a1 a2 a3
            f4 w1 = wr[ab * 3 + 1];      // a4 a5 b0 b1
            f4 w2 = wr[ab * 3 + 2];      // b2 b3 -- --
            float xv = xw[ab];
            float p = fmaf(w1.y, xv, w1.x);
            p = fmaf(p, xv, w0.w);
            p = fmaf(p, xv, w0.z);
            p = fmaf(p, xv, w0.y);
            p = fmaf(p, xv, w0.x);
            float q = fmaf(w2.y, xv, w2.x);
            q = fmaf(q, xv, w1.w);
            q = fmaf(q, xv, w1.z);
            float den = 1.0f + fabsf(xv * q);
            acc = fmaf(p, __builtin_amdgcn_rcpf(den), acc);
        }
    }

    // ---- cross-wave c-reduction; weights dead -> reuse wl ----
    __syncthreads();
    float* red = wl;
    red[cgrp * 128 + r * 32 + j] = acc;
    __syncthreads();
    if (tid < 128) {
        float s = 0.0f;
#pragma unroll
        for (int g = 0; g < 8; ++g) s += red[g * 128 + tid];
        out[f * (HH * WW) + i0 * WW + tid] = s;   // 128 contiguous floats
    }
}

extern "C" void kernel_launch(void* const* d_in, const int* in_sizes, int n_in,
                              void* d_out, int out_size, void* d_ws, size_t ws_size,
                              hipStream_t stream) {
    const float* x  = (const float*)d_in[0];
    const float* wn = (const float*)d_in[1];
    const float* wd = (const float*)d_in[2];
    float* out = (float*)d_out;
    (void)d_ws; (void)ws_size; (void)in_sizes; (void)n_in; (void)out_size;

    kan_main<<<NBLK, 1024, 0, stream>>>(x, wn, wd, out);
}